// Round 7
// baseline (869.831 us; speedup 1.0000x reference)
//
#include <hip/hip_runtime.h>

// SNNEncode — numerics LOCKED from round 6 (passed, absmax 2.4e-4):
//   xw  = fmaf chain k=0..15, acc init 0 (BLAS/Eigen sgemm order)
//   LIF = exact source order, separate f32 roundings, fp contract(off)
// DO NOT reorder any float op. This round changes SCHEDULING only.
//
// r6 counters: 236us, VALUBusy 20%, HBM 14.7%, occupancy 5.5% -> latency-
// bound (0.5 waves/SIMD, dependent 16-FMA chain serialized per step).
// Fixes:
//  1) Batch NB=8 xw chains (state-independent -> 8-way ILP, issue-bound).
//  2) Two-batch software pipeline with NAMED arrays (static indexing):
//     CX(B,t+8); LIF(A@t); CX(A,t+16); LIF(B@t+8) — next batch's FMA
//     stream hides the serial LIF chain's latency.
//  3) x rows read directly from global with thread-UNIFORM addresses ->
//     compiler emits s_load on the scalar pipe (0 VALU issue), no LDS,
//     no __syncthreads; waves fully independent.

constexpr int B  = 128;
constexpr int T  = 2000;
constexpr int IN = 16;
constexpr int H  = 256;
constexpr int BH = B * H;
constexpr int NB = 8;                    // batch of pipelined timesteps

__global__ __launch_bounds__(128, 1) void snn_pipe(
    const float* __restrict__ x, const float* __restrict__ Wm,
    const float* __restrict__ tau_syn, const float* __restrict__ tau_mem,
    float* __restrict__ out)
{
#pragma clang fp contract(off)
  const int tid = threadIdx.x;
  const int bid = blockIdx.x;
  const int b = bid >> 1;
  const int h = ((bid & 1) << 7) | tid;  // 0..255

  float w[IN];
#pragma unroll
  for (int k = 0; k < IN; ++k) w[k] = Wm[h * IN + k];

  float ts = tau_syn[h];
  ts = ts < 0.f ? 0.f : (ts > 1.f ? 1.f : ts);   // np.clip(tau_syn,0,1)
  float tm = tau_mem[h];
  tm = tm < 0.f ? 0.f : (tm > 1.f ? 1.f : tm);   // np.clip(tau_mem,0,1)
  const float nts = -ts;

  const float* xb = x + (size_t)b * T * IN;      // thread-uniform base
  float* op = out + (size_t)b * H + h;           // spikes[t,b,h], stride BH

  float vS = 0.f, iS = 0.f;

  float xwA[NB], xwB[NB];

  // 8 independent sequential-FMA chains; x addresses uniform -> s_load
  auto CX = [&](float* xw, int t0) {
#pragma unroll
    for (int j = 0; j < NB; ++j) {
      const float* xr = xb + (size_t)(t0 + j) * IN;
      float acc = 0.0f;
#pragma unroll
      for (int k = 0; k < IN; ++k)
        acc = __builtin_fmaf(xr[k], w[k], acc);  // LOCKED order
      xw[j] = acc;
    }
  };

  // serial LIF chain for NB steps (LOCKED op order) + spike stores
  auto LIF = [&](const float* xw) {
#pragma unroll
    for (int j = 0; j < NB; ++j) {
      const float t1 = iS - vS;
      const float t2 = tm * t1;
      const float vd = vS + t2;
      const float xm = vd - 1.0f;
      const bool  sp = xm > 0.0f;
      vS = sp ? 0.0f : vd;
      const float t3 = nts * iS;
      const float id = iS + t3;
      iS = id + xw[j];
      __builtin_nontemporal_store(sp ? 1.0f : 0.0f, op);
      op += BH;
    }
  };

  CX(xwA, 0);
  for (int t0 = 0; t0 < T; t0 += 2 * NB) {       // 125 iterations, no tail
    CX(xwB, t0 + NB);
    LIF(xwA);
    if (t0 + 2 * NB < T) CX(xwA, t0 + 2 * NB);
    LIF(xwB);
  }

  // final state: v_f then i_f, each [B,H] f32, after spikes
  out[(size_t)T * BH + (size_t)b * H + h]      = vS;
  out[(size_t)T * BH + BH + (size_t)b * H + h] = iS;
}

extern "C" void kernel_launch(void* const* d_in, const int* in_sizes, int n_in,
                              void* d_out, int out_size, void* d_ws, size_t ws_size,
                              hipStream_t stream) {
  const float* x  = (const float*)d_in[0];
  const float* W  = (const float*)d_in[1];
  const float* ts = (const float*)d_in[2];
  const float* tm = (const float*)d_in[3];
  float* out = (float*)d_out;
  hipLaunchKernelGGL(snn_pipe, dim3(B * 2), dim3(128), 0, stream,
                     x, W, ts, tm, out);
}

// Round 8
// 393.698 us; speedup vs baseline: 2.2094x; 2.2094x over previous
//
#include <hip/hip_runtime.h>

// SNNEncode — numerics LOCKED (r6 passed): xw = sequential fmaf chain k=0..15
// acc init 0; LIF in exact source order, separate roundings, fp contract(off).
// r7 lesson: at 2 waves/CU, global-load latency per small batch is unhidable;
// bulk LDS staging (r6) is mandatory. This round keeps r6's staging and adds:
//  - PAIR-PACKED LDS layout: lds f2[p][k] = {x[2p][k], x[2p+1][k]} so one
//    v_pk_fma_f32 advances two adjacent timesteps' chains (each half is a
//    bit-exact sequential fmaf chain -> rounding unchanged).
//  - 8-step batches, A/B pipelined with NAMED f2 regs (static indexing):
//    CX(B,bt+1); LIF(A); CX(A,bt+2); LIF(B) — packed-FMA stream hides the
//    serial LIF chain latency.
// block=128 (2 waves) = one b x half H; grid=256 = 1 block/CU.

constexpr int B  = 128;
constexpr int T  = 2000;
constexpr int IN = 16;
constexpr int H  = 256;
constexpr int TC = 128;                  // timesteps per LDS chunk
constexpr int NCH = (T + TC - 1) / TC;   // 16 chunks (last 80 rows)
constexpr int BH = B * H;

typedef float f2 __attribute__((ext_vector_type(2)));
typedef float f4 __attribute__((ext_vector_type(4)));

static __device__ __forceinline__ f2 fma2(f2 a, f2 b, f2 c) {
  return __builtin_elementwise_fma(a, b, c);   // -> v_pk_fma_f32 (IEEE fma per half)
}

__global__ __launch_bounds__(128, 1) void snn_pk(
    const float* __restrict__ x, const float* __restrict__ Wm,
    const float* __restrict__ tau_syn, const float* __restrict__ tau_mem,
    float* __restrict__ out)
{
#pragma clang fp contract(off)
  __shared__ float xs[TC * IN];          // 8 KiB, pair-packed: dword
                                         // (p*32 + 2k + half) = x[2p+half][k]
  const int tid = threadIdx.x;
  const int bid = blockIdx.x;
  const int b = bid >> 1;
  const int h = ((bid & 1) << 7) | tid;  // 0..255

  float w[IN];
#pragma unroll
  for (int k = 0; k < IN; ++k) w[k] = Wm[h * IN + k];

  float ts = tau_syn[h];
  ts = ts < 0.f ? 0.f : (ts > 1.f ? 1.f : ts);
  float tm = tau_mem[h];
  tm = tm < 0.f ? 0.f : (tm > 1.f ? 1.f : tm);
  const float nts = -ts;

  const float* xb = x + (size_t)b * T * IN;
  float* op = out + (size_t)b * H + h;           // spikes[t,b,h], stride BH

  float vS = 0.f, iS = 0.f;

  const f2* xsp = reinterpret_cast<const f2*>(xs);   // pair p, k: xsp[p*16+k]

  // compute xw for batch bt (8 rows = 4 pairs) into 4 named f2 accumulators
  auto CX = [&](f2& d0, f2& d1, f2& d2, f2& d3, int bt) {
    const f2* q = xsp + bt * 64;                 // 4 pairs * 16
    f2 a0 = (f2)(0.f), a1 = (f2)(0.f), a2 = (f2)(0.f), a3 = (f2)(0.f);
#pragma unroll
    for (int k = 0; k < IN; ++k) {
      const f2 wk = (f2)(w[k]);                  // splat
      a0 = fma2(q[k],      wk, a0);              // LOCKED chain per half
      a1 = fma2(q[16 + k], wk, a1);
      a2 = fma2(q[32 + k], wk, a2);
      a3 = fma2(q[48 + k], wk, a3);
    }
    d0 = a0; d1 = a1; d2 = a2; d3 = a3;
  };

  // serial LIF for 8 steps (LOCKED op order) + spike stores
  auto LIF = [&](f2 d0, f2 d1, f2 d2, f2 d3) {
    float xwv[8] = {d0.x, d0.y, d1.x, d1.y, d2.x, d2.y, d3.x, d3.y};
#pragma unroll
    for (int j = 0; j < 8; ++j) {
      const float t1 = iS - vS;
      const float t2 = tm * t1;
      const float vd = vS + t2;
      const float xm = vd - 1.0f;
      const bool  sp = xm > 0.0f;
      vS = sp ? 0.0f : vd;
      const float t3 = nts * iS;
      const float id = iS + t3;
      iS = id + xwv[j];
      __builtin_nontemporal_store(sp ? 1.0f : 0.0f, op);
      op += BH;
    }
  };

  f2 A0, A1, A2, A3, B0, B1, B2, B3;

  for (int c = 0; c < NCH; ++c) {
    const int t0   = c * TC;
    const int rows = min(TC, T - t0);
    const int nf4  = rows * IN / 4;              // 512 or 320 f4

    __syncthreads();                             // previous chunk consumed
    {
      const f4* src = reinterpret_cast<const f4*>(xb + (size_t)t0 * IN);
      for (int i4 = tid; i4 < nf4; i4 += 128) {
        const f4 v4 = src[i4];                   // coalesced 16B
        const int r  = i4 >> 2;                  // row in chunk
        const int k0 = (i4 & 3) << 2;            // first col of this f4
        const int base = ((r >> 1) << 5) | (r & 1);  // pair base + half
#pragma unroll
        for (int e = 0; e < 4; ++e)
          xs[base + ((k0 + e) << 1)] = v4[e];    // 2-way bank alias: free
      }
    }
    __syncthreads();                             // staging visible

    const int nbat = rows >> 3;                  // 16 or 10 (both even)
    CX(A0, A1, A2, A3, 0);
    for (int bt = 0; bt < nbat; bt += 2) {
      CX(B0, B1, B2, B3, bt + 1);
      LIF(A0, A1, A2, A3);
      if (bt + 2 < nbat) CX(A0, A1, A2, A3, bt + 2);
      LIF(B0, B1, B2, B3);
    }
  }

  // final state: v_f then i_f, each [B,H] f32, after spikes
  out[(size_t)T * BH + (size_t)b * H + h]      = vS;
  out[(size_t)T * BH + BH + (size_t)b * H + h] = iS;
}

extern "C" void kernel_launch(void* const* d_in, const int* in_sizes, int n_in,
                              void* d_out, int out_size, void* d_ws, size_t ws_size,
                              hipStream_t stream) {
  const float* x  = (const float*)d_in[0];
  const float* W  = (const float*)d_in[1];
  const float* ts = (const float*)d_in[2];
  const float* tm = (const float*)d_in[3];
  float* out = (float*)d_out;
  hipLaunchKernelGGL(snn_pk, dim3(B * 2), dim3(128), 0, stream,
                     x, W, ts, tm, out);
}

// Round 9
// 387.658 us; speedup vs baseline: 2.2438x; 1.0156x over previous
//
#include <hip/hip_runtime.h>

// SNNEncode — numerics LOCKED (r6/r8 passed, absmax 2.441e-4):
//   xw = sequential fmaf chain k=0..15, acc init 0 (per (t,h))
//   LIF = exact source order, separate f32 roundings, fp contract(off)
// r8 counters (183us, VALUBusy 18%, occ 5.5%): latency-bound; root cause =
// x BROADCAST through LDS (64-lane register writeback for 8B unique data)
// + unfillable LIF bubbles at 1 wave/SIMD.
// This round: phase-split, wave-private, broadcast-free.
//   P1 (lane=t): x per-lane from global; per h' read W from LDS; pk-FMA
//     computes {t, t+64} dots (each half = locked fmaf chain); write xw
//     to wave-private LDS [t][h'] (pad 65).
//   P2 (lane=h): per t ONE stride-1 ds_read_b32 feeds 64 lanes' LIF.
//   P1(tile+1) fused into P2(tile) loop (xw double-buffered) for overlap.
// No __syncthreads (all LDS wave-private). block=128 (2 waves)=one b x half
// H; grid=256 = 1 block/CU.

constexpr int B  = 128;
constexpr int T  = 2000;
constexpr int IN = 16;
constexpr int H  = 256;
constexpr int BH = B * H;
constexpr int TT = 128;                  // t-tile
constexpr int NT = (T + TT - 1) / TT;    // 16 tiles, last = 80 rows

typedef float f2 __attribute__((ext_vector_type(2)));
typedef float f4 __attribute__((ext_vector_type(4)));

static __device__ __forceinline__ f2 fma2(f2 a, f2 b, f2 c) {
  return __builtin_elementwise_fma(a, b, c);   // v_pk_fma_f32, IEEE per half
}

__global__ __launch_bounds__(128, 1) void snn_split(
    const float* __restrict__ x, const float* __restrict__ Wm,
    const float* __restrict__ tau_syn, const float* __restrict__ tau_mem,
    float* __restrict__ out)
{
#pragma clang fp contract(off)
  __shared__ float xw[2][2][TT][65];     // [wave][buf][t][h'], pad 65
  __shared__ float wl[2][64][16];        // [wave][h'][k]
  const int tid = threadIdx.x, bid = blockIdx.x;
  const int b = bid >> 1, hh = bid & 1;
  const int w = tid >> 6, l = tid & 63;
  const int hbase = (hh << 7) + (w << 6);
  const int h = hbase + l;

  // stage this wave's 64 W rows into wave-private LDS (coalesced, once)
  {
    const f4* src = reinterpret_cast<const f4*>(Wm + hbase * IN);
    f4* dst = reinterpret_cast<f4*>(&wl[w][0][0]);
#pragma unroll
    for (int i = 0; i < 4; ++i) dst[l + 64 * i] = src[l + 64 * i];
  }

  float ts = tau_syn[h]; ts = ts < 0.f ? 0.f : (ts > 1.f ? 1.f : ts);
  float tm = tau_mem[h]; tm = tm < 0.f ? 0.f : (tm > 1.f ? 1.f : tm);
  const float nts = -ts;

  const float* xb = x + (size_t)b * T * IN;
  float* op = out + (size_t)b * H + h;   // spikes[t,b,h], stride BH
  float vS = 0.f, iS = 0.f;

  f4 xa4[4], xb4[4];                     // current P1 tile's two x rows

  // load per-lane x rows for tile (rA = t0+l, rB = t0+64+l clamped)
  auto LOADX = [&](int tile) {
    const int t0 = tile * TT;
    const int rA = t0 + l;
    int rB = t0 + 64 + l; rB = rB > (T - 1) ? (T - 1) : rB;  // tail clamp
    const f4* pa = reinterpret_cast<const f4*>(xb + (size_t)rA * IN);
    const f4* pb = reinterpret_cast<const f4*>(xb + (size_t)rB * IN);
#pragma unroll
    for (int i = 0; i < 4; ++i) { xa4[i] = pa[i]; xb4[i] = pb[i]; }
  };

  // one P1 column: dots for (t0+l, hp) and (t0+64+l, hp); LOCKED chains
  auto P1COL = [&](int hp, int bf) {
    const f4* wrow = reinterpret_cast<const f4*>(&wl[w][hp][0]);
    const f4 wv[4] = {wrow[0], wrow[1], wrow[2], wrow[3]};
    f2 acc; acc.x = 0.f; acc.y = 0.f;
#pragma unroll
    for (int k = 0; k < 16; ++k) {
      const float wk = wv[k >> 2][k & 3];
      f2 ax; ax.x = xa4[k >> 2][k & 3]; ax.y = xb4[k >> 2][k & 3];
      f2 ws; ws.x = wk; ws.y = wk;
      acc = fma2(ax, ws, acc);           // two locked fmaf chains
    }
    xw[w][bf][l][hp]      = acc.x;
    xw[w][bf][64 + l][hp] = acc.y;
  };

  // one LIF step from xw[bf][j][l]; LOCKED op order
  auto P2STEP = [&](int j, int bf) {
    const float xwv = xw[w][bf][j][l];   // stride-1 read: 64 useful values
    const float t1 = iS - vS;
    const float t2 = tm * t1;
    const float vd = vS + t2;
    const float xm = vd - 1.0f;
    const bool  sp = xm > 0.0f;
    vS = sp ? 0.0f : vd;
    const float t3 = nts * iS;
    const float id = iS + t3;
    iS = id + xwv;
    __builtin_nontemporal_store(sp ? 1.0f : 0.0f, op);
    op += BH;
  };

  // prologue: produce tile 0 into buf 0
  LOADX(0);
#pragma unroll 2
  for (int hp = 0; hp < 64; ++hp) P1COL(hp, 0);

  int bf = 0;
  for (int tile = 0; tile < NT; ++tile) {
    const bool hasNext = (tile + 1 < NT);
    const int rows = hasNext ? TT : (T - (NT - 1) * TT);   // 128 or 80
    if (hasNext) LOADX(tile + 1);
    if (hasNext) {
#pragma unroll 8
      for (int j = 0; j < TT; ++j) {     // fused: P1(next) woven into P2(cur)
        if ((j & 1) == 0) P1COL(j >> 1, bf ^ 1);
        P2STEP(j, bf);
      }
    } else {
#pragma unroll 8
      for (int j = 0; j < rows; ++j) P2STEP(j, bf);  // tail: 80 steps
    }
    bf ^= 1;
  }

  // final state: v_f then i_f, each [B,H] f32, after spikes
  out[(size_t)T * BH + (size_t)b * H + h]      = vS;
  out[(size_t)T * BH + BH + (size_t)b * H + h] = iS;
}

extern "C" void kernel_launch(void* const* d_in, const int* in_sizes, int n_in,
                              void* d_out, int out_size, void* d_ws, size_t ws_size,
                              hipStream_t stream) {
  const float* x  = (const float*)d_in[0];
  const float* W  = (const float*)d_in[1];
  const float* ts = (const float*)d_in[2];
  const float* tm = (const float*)d_in[3];
  float* out = (float*)d_out;
  hipLaunchKernelGGL(snn_split, dim3(B * 2), dim3(128), 0, stream,
                     x, W, ts, tm, out);
}